// Round 1
// baseline (317.349 us; speedup 1.0000x reference)
//
#include <hip/hip_runtime.h>
#include <stdint.h>

typedef float f32x4 __attribute__((ext_vector_type(4)));
typedef __bf16 bf16x8 __attribute__((ext_vector_type(8)));
typedef unsigned short us8 __attribute__((ext_vector_type(8)));
typedef unsigned short us4 __attribute__((ext_vector_type(4)));
typedef unsigned int u32;

#define MFMA16(A, B, C) __builtin_amdgcn_mfma_f32_16x16x32_bf16( \
    __builtin_bit_cast(bf16x8, (A)), __builtin_bit_cast(bf16x8, (B)), (C), 0, 0, 0)

__device__ __forceinline__ unsigned short f2bf(float f) {
  u32 u = __builtin_bit_cast(u32, f);
  u = u + 0x7fffu + ((u >> 16) & 1u);   // RNE
  return (unsigned short)(u >> 16);
}
__device__ __forceinline__ float bf2f(unsigned short b) {
  u32 u = ((u32)b) << 16;
  return __builtin_bit_cast(float, u);
}
// async global->LDS, 16B per lane. LDS dest must be wave-uniform base (HW adds lane*16).
__device__ __forceinline__ void gload16(const void* g, void* lds) {
  __builtin_amdgcn_global_load_lds((const __attribute__((address_space(1))) u32*)g,
                                   (__attribute__((address_space(3))) u32*)lds, 16, 0, 0);
}

// ---------------- fp32 -> bf16 conversion of x and weights ----------------
__global__ __launch_bounds__(256) void convert_all(
    const float* __restrict__ x, const float* __restrict__ wq, const float* __restrict__ wk,
    const float* __restrict__ wv, const float* __restrict__ wo,
    unsigned short* __restrict__ xb, unsigned short* __restrict__ wcat,
    unsigned short* __restrict__ wob) {
  int tid = blockIdx.x * 256 + threadIdx.x;
  int nth = gridDim.x * 256;
  const float* srcs[5] = {x, wq, wk, wv, wo};
  unsigned short* dsts[5] = {xb, wcat, wcat + 4194304, wcat + 8388608, wob};
  const int n4s[5] = {2097152, 1048576, 1048576, 1048576, 1048576};
#pragma unroll
  for (int sg = 0; sg < 5; ++sg) {
    const float4* s = (const float4*)srcs[sg];
    us4* d = (us4*)dsts[sg];
    int n4 = n4s[sg];
    for (int i = tid; i < n4; i += nth) {
      float4 v = s[i];
      us4 o;
      o[0] = f2bf(v.x); o[1] = f2bf(v.y); o[2] = f2bf(v.z); o[3] = f2bf(v.w);
      d[i] = o;
    }
  }
}

// ---------------- bf16 GEMM, C = A * B^T (+bias/epilogue) ----------------
// A: [M][K] bf16 row-major.  B: [N][K] bf16 row-major.  128x128 tile, BK=32,
// 4 waves (each 64x64 = 4x4 fragments of 16x16x32).
// EPI=0: QKV epilogue -> scatter q/k [BH][S][hd] bf16 (+bq), v transposed [BH][hd][S] (+bv)
// EPI=1: fp32 out + bias
template <int EPI>
__global__ __launch_bounds__(256) void gemm_bt(
    const unsigned short* __restrict__ A, const unsigned short* __restrict__ B,
    int M, int N, int K, int nTN,
    float* __restrict__ outF, const float* __restrict__ bias,
    unsigned short* __restrict__ qb, unsigned short* __restrict__ kb,
    unsigned short* __restrict__ vtb, const float* __restrict__ bq,
    const float* __restrict__ bv) {
  __shared__ alignas(16) unsigned short lsA[128 * 32];
  __shared__ alignas(16) unsigned short lsB[128 * 32];
  int bid = (int)blockIdx.x;
  int nwg = (int)gridDim.x;
  {  // bijective XCD-aware swizzle (m204)
    int qq = nwg >> 3, rr = nwg & 7;
    int xcd = bid & 7, idx = bid >> 3;
    bid = (xcd < rr ? xcd * (qq + 1) : rr * (qq + 1) + (xcd - rr) * qq) + idx;
  }
  int tm = bid / nTN, tn = bid % nTN;
  int t = (int)threadIdx.x, l = t & 63, w = t >> 6;
  int g = l >> 4, ln = l & 15;
  int wr = w >> 1, wc = w & 1;

  f32x4 acc[4][4] = {};

  const int KT = K >> 5;
  for (int kt = 0; kt < KT; ++kt) {
    __syncthreads();
#pragma unroll
    for (int i = 0; i < 2; ++i) {
      int fb = i * 4096 + w * 1024;      // wave-uniform LDS byte base
      int flat = fb + l * 16;            // this lane's slot
      int row = flat >> 6, colb = flat & 63;
      gload16(A + ((size_t)(tm * 128 + row) * K + kt * 32 + (colb >> 1)), (char*)lsA + fb);
      gload16(B + ((size_t)(tn * 128 + row) * K + kt * 32 + (colb >> 1)), (char*)lsB + fb);
    }
    __syncthreads();
    us8 af[4], bfr[4];
#pragma unroll
    for (int mf = 0; mf < 4; ++mf)
      af[mf] = *(const us8*)&lsA[(wr * 64 + mf * 16 + ln) * 32 + g * 8];
#pragma unroll
    for (int nf = 0; nf < 4; ++nf)
      bfr[nf] = *(const us8*)&lsB[(wc * 64 + nf * 16 + ln) * 32 + g * 8];
#pragma unroll
    for (int mf = 0; mf < 4; ++mf)
#pragma unroll
      for (int nf = 0; nf < 4; ++nf)
        acc[mf][nf] = MFMA16(af[mf], bfr[nf], acc[mf][nf]);
  }

  if (EPI == 1) {
#pragma unroll
    for (int mf = 0; mf < 4; ++mf)
#pragma unroll
      for (int nf = 0; nf < 4; ++nf) {
        int n = tn * 128 + wc * 64 + nf * 16 + ln;
        float bz = bias[n];
#pragma unroll
        for (int r = 0; r < 4; ++r) {
          int m = tm * 128 + wr * 64 + mf * 16 + g * 4 + r;
          outF[(size_t)m * N + n] = acc[mf][nf][r] + bz;
        }
      }
  } else {
#pragma unroll
    for (int mf = 0; mf < 4; ++mf)
#pragma unroll
      for (int nf = 0; nf < 4; ++nf) {
        int n6 = tn * 128 + wc * 64 + nf * 16 + ln;
        int sel = n6 >> 11, d = n6 & 2047, h = d >> 7, hd = d & 127;
        int m0 = tm * 128 + wr * 64 + mf * 16 + g * 4;
        int b = m0 >> 11, s0 = m0 & 2047;
        if (sel == 2) {  // v -> transposed [bh][hd][S], 4 consecutive s pack to 8B
          float badd = bv[d];
          us4 pk;
#pragma unroll
          for (int r = 0; r < 4; ++r) pk[r] = f2bf(acc[mf][nf][r] + badd);
          *(us4*)&vtb[((size_t)(b * 16 + h) * 128 + hd) * 2048 + s0] = pk;
        } else {  // q/k -> [bh][S][hd]
          unsigned short* dst = sel ? kb : qb;
          float badd = sel ? 0.f : bq[d];
#pragma unroll
          for (int r = 0; r < 4; ++r)
            dst[((size_t)(b * 16 + h) * 2048 + (s0 + r)) * 128 + hd] =
                f2bf(acc[mf][nf][r] + badd);
        }
      }
  }
}

// ---------------- interleaved RoPE on q,k in place ----------------
__global__ __launch_bounds__(256) void rope_k(u32* __restrict__ q, u32* __restrict__ k) {
  int idx = blockIdx.x * 256 + threadIdx.x;  // exactly 2*16*2048*64
  int i = idx & 63;
  int s = (idx >> 6) & 2047;
  // inv_freq = 10000^(-i/64) = 2^(-i*log2(10000)/64)
  float ang = (float)s * exp2f(-(float)i * 0.2076205059304703f);
  float sv, cv;
  sincosf(ang, &sv, &cv);
  u32 qu = q[idx];
  float a0 = bf2f((unsigned short)(qu & 0xffff)), a1 = bf2f((unsigned short)(qu >> 16));
  q[idx] = (u32)f2bf(a0 * cv - a1 * sv) | ((u32)f2bf(a1 * cv + a0 * sv) << 16);
  u32 ku = k[idx];
  float b0 = bf2f((unsigned short)(ku & 0xffff)), b1 = bf2f((unsigned short)(ku >> 16));
  k[idx] = (u32)f2bf(b0 * cv - b1 * sv) | ((u32)f2bf(b1 * cv + b0 * sv) << 16);
}

// ---------------- causal flash attention ----------------
// 8 waves x 16 q-rows = 128-row Q tile; KV tile = 64. Swapped QK^T (S^T = K*Q^T)
// so each lane's P column is its own q-row -> packed LDS round-trip for PV A-frags.
// Block handles Q-tiles (qt, 15-qt) for causal balance. K/V^T LDS XOR-swizzled (G4).
__global__ __launch_bounds__(512) void attn_k(
    const unsigned short* __restrict__ qg, const unsigned short* __restrict__ kg,
    const unsigned short* __restrict__ vtg, unsigned short* __restrict__ ab) {
  __shared__ alignas(16) unsigned short Kl[64 * 128];   // [key][hd], swizzled
  __shared__ alignas(16) unsigned short Vl[128 * 64];   // [hd][key], swizzled
  __shared__ alignas(16) unsigned short Pl[8][16 * 72]; // per wave [qrow][key+pad]
  int bh = (int)blockIdx.x & 31;
  int pr = (int)blockIdx.x >> 5;
  int t = (int)threadIdx.x, l = t & 63, w = t >> 6;
  int g = l >> 4, ln = l & 15;
  int b = bh >> 4, h = bh & 15;
  const size_t bq0 = (size_t)bh * 2048 * 128;

#pragma unroll 1
  for (int half = 0; half < 2; ++half) {
    int qt = half ? 15 - pr : pr;
    int qbase = qt * 128;
    int qrow = qbase + w * 16 + ln;
    us8 qf[4];
#pragma unroll
    for (int kf = 0; kf < 4; ++kf)
      qf[kf] = *(const us8*)&qg[bq0 + (size_t)qrow * 128 + kf * 32 + g * 8];
    f32x4 o[8] = {};
    float mrow = -1e30f, lrow = 0.f;
    int nkt = (qbase >> 6) + 2;
#pragma unroll 1
    for (int kt = 0; kt < nkt; ++kt) {
      __syncthreads();
#pragma unroll
      for (int i = 0; i < 2; ++i) {
        int fb = i * 8192 + w * 1024;
        int flat = fb + l * 16;
        int row = flat >> 8, colb = flat & 255;
        int sc = colb ^ ((row & 7) << 4);  // pre-swizzled global source (m173)
        gload16(kg + (bq0 + (size_t)(kt * 64 + row) * 128 + (sc >> 1)), (char*)Kl + fb);
        int rv = flat >> 7, cv2 = flat & 127;
        int scv = cv2 ^ ((rv & 7) << 4);
        gload16(vtg + (bq0 + (size_t)rv * 2048 + kt * 64 + (scv >> 1)), (char*)Vl + fb);
      }
      __syncthreads();
      // S^T = K * Q^T : D[key_local][qrow_local]
      f32x4 st[4];
#pragma unroll
      for (int kfr = 0; kfr < 4; ++kfr) {
        f32x4 acc = {};
        int row = kfr * 16 + ln;
        int swz = (row & 7) << 4;
#pragma unroll
        for (int kf = 0; kf < 4; ++kf) {
          us8 kfrag = *(const us8*)((const char*)Kl + row * 256 + ((kf * 64 + g * 16) ^ swz));
          acc = MFMA16(kfrag, qf[kf], acc);
        }
        st[kfr] = acc;
      }
      // scale + causal mask; row max (this lane's column = its q-row)
      float pmax = -1e30f;
#pragma unroll
      for (int kfr = 0; kfr < 4; ++kfr)
#pragma unroll
        for (int r = 0; r < 4; ++r) {
          int key = kt * 64 + kfr * 16 + g * 4 + r;
          float sv = key <= qrow ? st[kfr][r] * 0.08838834764831845f : -1e30f;
          st[kfr][r] = sv;
          pmax = fmaxf(pmax, sv);
        }
      pmax = fmaxf(pmax, __shfl_xor(pmax, 16));
      pmax = fmaxf(pmax, __shfl_xor(pmax, 32));
      // defer-max (THR=8): rescale only on real growth
      if (__ballot(pmax > mrow + 8.f)) {
        float mnew = pmax > mrow + 8.f ? pmax : mrow;
        float corr = exp2f((mrow - mnew) * 1.44269504f);
        mrow = mnew;
        lrow *= corr;
#pragma unroll
        for (int r = 0; r < 4; ++r) {
          float cr = __shfl(corr, g * 4 + r);  // corr for O-row (4g+r) lives at lane 4g+r
#pragma unroll
          for (int nf = 0; nf < 8; ++nf) o[nf][r] *= cr;
        }
      }
      // P = exp(S - m), pack to per-wave LDS [qrow][key]
      float lsum = 0.f;
#pragma unroll
      for (int kfr = 0; kfr < 4; ++kfr) {
        us4 pk;
#pragma unroll
        for (int r = 0; r < 4; ++r) {
          float p = exp2f((st[kfr][r] - mrow) * 1.44269504f);
          lsum += p;
          pk[r] = f2bf(p);
        }
        *(us4*)&Pl[w][ln * 72 + kfr * 16 + g * 4] = pk;
      }
      lsum += __shfl_xor(lsum, 16);
      lsum += __shfl_xor(lsum, 32);
      lrow += lsum;
      // PV: O[qrow_local][hd]
#pragma unroll
      for (int kf2 = 0; kf2 < 2; ++kf2) {
        us8 pa = *(const us8*)&Pl[w][ln * 72 + kf2 * 32 + g * 8];
#pragma unroll
        for (int nf = 0; nf < 8; ++nf) {
          int row = nf * 16 + ln;
          us8 vb = *(const us8*)((const char*)Vl + row * 128 +
                                 ((kf2 * 64 + g * 16) ^ ((row & 7) << 4)));
          o[nf] = MFMA16(pa, vb, o[nf]);
        }
      }
    }  // kt
    float invl = 1.f / lrow;
#pragma unroll
    for (int r = 0; r < 4; ++r) {
      float ir = __shfl(invl, g * 4 + r);
      int srow = qbase + w * 16 + g * 4 + r;
      size_t base = ((size_t)b * 2048 + srow) * 2048 + h * 128 + ln;
#pragma unroll
      for (int nf = 0; nf < 8; ++nf) ab[base + (size_t)nf * 16] = f2bf(o[nf][r] * ir);
    }
  }  // half
}

extern "C" void kernel_launch(void* const* d_in, const int* in_sizes, int n_in,
                              void* d_out, int out_size, void* d_ws, size_t ws_size,
                              hipStream_t stream) {
  const float* x  = (const float*)d_in[0];
  const float* Wq = (const float*)d_in[1];
  const float* bq = (const float*)d_in[2];
  const float* Wk = (const float*)d_in[3];
  const float* Wv = (const float*)d_in[4];
  const float* bv = (const float*)d_in[5];
  const float* Wo = (const float*)d_in[6];
  const float* bo = (const float*)d_in[7];
  float* out = (float*)d_out;

  unsigned short* ws = (unsigned short*)d_ws;
  unsigned short* xb   = ws;                // 8388608 elems (x bf16; later reused as attn out)
  unsigned short* wcat = xb + 8388608;      // 12582912 (Wq|Wk|Wv rows, [6144][2048])
  unsigned short* wob  = wcat + 12582912;   // 4194304
  unsigned short* qb   = wob + 4194304;     // 8388608  [32][2048][128]
  unsigned short* kb   = qb + 8388608;      // 8388608
  unsigned short* vtb  = kb + 8388608;      // 8388608  [32][128][2048] (transposed)
  // total 100.7 MB of d_ws

  convert_all<<<2048, 256, 0, stream>>>(x, Wq, Wk, Wv, Wo, xb, wcat, wob);
  gemm_bt<0><<<1536, 256, 0, stream>>>(xb, wcat, 4096, 6144, 2048, 48,
                                       nullptr, nullptr, qb, kb, vtb, bq, bv);
  rope_k<<<16384, 256, 0, stream>>>((u32*)qb, (u32*)kb);
  attn_k<<<256, 512, 0, stream>>>(qb, kb, vtb, xb /* a_buf alias */);
  gemm_bt<1><<<512, 256, 0, stream>>>(xb, wob, 4096, 2048, 2048, 16,
                                      out, bo, nullptr, nullptr, nullptr, nullptr, nullptr);
}

// Round 2
// 284.407 us; speedup vs baseline: 1.1158x; 1.1158x over previous
//
#include <hip/hip_runtime.h>
#include <stdint.h>

typedef float f32x4 __attribute__((ext_vector_type(4)));
typedef __bf16 bf16x8 __attribute__((ext_vector_type(8)));
typedef unsigned short us8 __attribute__((ext_vector_type(8)));
typedef unsigned short us4 __attribute__((ext_vector_type(4)));
typedef unsigned int u32;

#define MFMA16(A, B, C) __builtin_amdgcn_mfma_f32_16x16x32_bf16( \
    __builtin_bit_cast(bf16x8, (A)), __builtin_bit_cast(bf16x8, (B)), (C), 0, 0, 0)

__device__ __forceinline__ unsigned short f2bf(float f) {
  u32 u = __builtin_bit_cast(u32, f);
  u = u + 0x7fffu + ((u >> 16) & 1u);   // RNE
  return (unsigned short)(u >> 16);
}
__device__ __forceinline__ float bf2f(unsigned short b) {
  u32 u = ((u32)b) << 16;
  return __builtin_bit_cast(float, u);
}
// async global->LDS, 16B per lane. LDS dest must be wave-uniform base (HW adds lane*16).
__device__ __forceinline__ void gload16(const void* g, void* lds) {
  __builtin_amdgcn_global_load_lds((const __attribute__((address_space(1))) u32*)g,
                                   (__attribute__((address_space(3))) u32*)lds, 16, 0, 0);
}

// ---------------- fp32 -> bf16 conversion of x and weights ----------------
__global__ __launch_bounds__(256) void convert_all(
    const float* __restrict__ x, const float* __restrict__ wq, const float* __restrict__ wk,
    const float* __restrict__ wv, const float* __restrict__ wo,
    unsigned short* __restrict__ xb, unsigned short* __restrict__ wcat,
    unsigned short* __restrict__ wob) {
  int tid = blockIdx.x * 256 + threadIdx.x;
  int nth = gridDim.x * 256;
  const float* srcs[5] = {x, wq, wk, wv, wo};
  unsigned short* dsts[5] = {xb, wcat, wcat + 4194304, wcat + 8388608, wob};
  const int n4s[5] = {2097152, 1048576, 1048576, 1048576, 1048576};
#pragma unroll
  for (int sg = 0; sg < 5; ++sg) {
    const float4* s = (const float4*)srcs[sg];
    us4* d = (us4*)dsts[sg];
    int n4 = n4s[sg];
    for (int i = tid; i < n4; i += nth) {
      float4 v = s[i];
      us4 o;
      o[0] = f2bf(v.x); o[1] = f2bf(v.y); o[2] = f2bf(v.z); o[3] = f2bf(v.w);
      d[i] = o;
    }
  }
}

// ---------------- bf16 GEMM, C = A * B^T, deep-prefetch counted-vmcnt ----------------
// BM=128, BN=256, BK=32; 512 threads = 8 waves (2M x 4N), per-wave 64x64 (4x4 frags).
// 4 LDS tile-buffers (A 8KB + B 16KB = 24KB each, 96KB total), staged 3 tiles ahead
// via global_load_lds; one raw s_barrier per K-tile; vmcnt(6) steady state (never 0
// until the peeled tail). BK=32 rows are 64B so fragment reads are dense contiguous
// 1024B blocks -> conflict-free without swizzle; staging stays linear (rule 21 ok).
// EPI=0: QKV epilogue -> scatter q/k [BH][S][hd] bf16 (+bq), v transposed [BH][hd][S] (+bv)
// EPI=1: fp32 out + bias
template <int EPI>
__global__ __launch_bounds__(512, 2) void gemm2(
    const unsigned short* __restrict__ A, const unsigned short* __restrict__ B,
    int nTN, int N,
    float* __restrict__ outF, const float* __restrict__ bias,
    unsigned short* __restrict__ qb, unsigned short* __restrict__ kb,
    unsigned short* __restrict__ vtb, const float* __restrict__ bq,
    const float* __restrict__ bv) {
  constexpr int K = 2048, KT = 64;
  __shared__ alignas(16) char L[4 * 24576];
  int bid = (int)blockIdx.x, nwg = (int)gridDim.x;
  {  // XCD-aware swizzle; all our grids have nwg % 8 == 0 (768, 256)
    int qq = nwg >> 3;
    int xcd = bid & 7, idx = bid >> 3;
    bid = xcd * qq + idx;
  }
  int tm = bid / nTN, tn = bid % nTN;
  int t = (int)threadIdx.x, l = t & 63, w = t >> 6;
  int g = l >> 4, ln = l & 15;
  int wr = w >> 2, wc = w & 3;
  // per-lane staging source pointers: lane covers row (w*16 + l/4), 16B chunk (l&3)
  const unsigned short* Ab =
      A + (size_t)(tm * 128 + w * 16 + (l >> 2)) * K + (l & 3) * 8;
  const unsigned short* Bb =
      B + (size_t)(tn * 256 + w * 16 + (l >> 2)) * K + (l & 3) * 8;
  f32x4 acc[4][4] = {};

#define STAGE(tile) do {                                                      \
    char* Lb = L + ((tile) & 3) * 24576 + w * 1024;                           \
    int kc = (tile) * 32;                                                     \
    gload16(Ab + kc, Lb);                     /* A rows 0..127   */           \
    gload16(Bb + kc, Lb + 8192);              /* B rows 0..127   */           \
    gload16(Bb + (size_t)128 * K + kc, Lb + 16384); /* B rows 128..255 */     \
  } while (0)

#define GITER(kt, VM) do {                                                    \
    asm volatile("s_waitcnt vmcnt(" #VM ")" ::: "memory");                    \
    __builtin_amdgcn_s_barrier();                                             \
    __builtin_amdgcn_sched_barrier(0);                                        \
    asm volatile("" ::: "memory");                                            \
    if ((kt) + 3 < KT) STAGE((kt) + 3);                                       \
    const unsigned short* Lc = (const unsigned short*)(L + ((kt) & 3) * 24576); \
    us8 af[4], bfr[4];                                                        \
    _Pragma("unroll") for (int mf = 0; mf < 4; ++mf)                          \
      af[mf] = *(const us8*)&Lc[(wr * 64 + mf * 16 + ln) * 32 + g * 8];       \
    _Pragma("unroll") for (int nf = 0; nf < 4; ++nf)                          \
      bfr[nf] = *(const us8*)&Lc[4096 + (wc * 64 + nf * 16 + ln) * 32 + g * 8]; \
    __builtin_amdgcn_s_setprio(1);                                            \
    _Pragma("unroll") for (int mf = 0; mf < 4; ++mf)                          \
      _Pragma("unroll") for (int nf = 0; nf < 4; ++nf)                        \
        acc[mf][nf] = MFMA16(af[mf], bfr[nf], acc[mf][nf]);                   \
    __builtin_amdgcn_s_setprio(0);                                            \
  } while (0)

  STAGE(0); STAGE(1); STAGE(2);
#pragma unroll 1
  for (int kt = 0; kt < KT - 2; ++kt) GITER(kt, 6);
  GITER(KT - 2, 3);
  GITER(KT - 1, 0);
#undef STAGE
#undef GITER

  if (EPI == 1) {
#pragma unroll
    for (int mf = 0; mf < 4; ++mf)
#pragma unroll
      for (int nf = 0; nf < 4; ++nf) {
        int n = tn * 256 + wc * 64 + nf * 16 + ln;
        float bz = bias[n];
#pragma unroll
        for (int r = 0; r < 4; ++r) {
          int m = tm * 128 + wr * 64 + mf * 16 + g * 4 + r;
          outF[(size_t)m * N + n] = acc[mf][nf][r] + bz;
        }
      }
  } else {
#pragma unroll
    for (int mf = 0; mf < 4; ++mf)
#pragma unroll
      for (int nf = 0; nf < 4; ++nf) {
        int n6 = tn * 256 + wc * 64 + nf * 16 + ln;
        int sel = n6 >> 11, d = n6 & 2047, h = d >> 7, hd = d & 127;
        int m0 = tm * 128 + wr * 64 + mf * 16 + g * 4;
        int b = m0 >> 11, s0 = m0 & 2047;
        if (sel == 2) {  // v -> transposed [bh][hd][S], 4 consecutive s pack to 8B
          float badd = bv[d];
          us4 pk;
#pragma unroll
          for (int r = 0; r < 4; ++r) pk[r] = f2bf(acc[mf][nf][r] + badd);
          *(us4*)&vtb[((size_t)(b * 16 + h) * 128 + hd) * 2048 + s0] = pk;
        } else {  // q/k -> [bh][S][hd]
          unsigned short* dst = sel ? kb : qb;
          float badd = sel ? 0.f : bq[d];
#pragma unroll
          for (int r = 0; r < 4; ++r)
            dst[((size_t)(b * 16 + h) * 2048 + (s0 + r)) * 128 + hd] =
                f2bf(acc[mf][nf][r] + badd);
        }
      }
  }
}

// ---------------- interleaved RoPE on q,k in place ----------------
__global__ __launch_bounds__(256) void rope_k(u32* __restrict__ q, u32* __restrict__ k) {
  int idx = blockIdx.x * 256 + threadIdx.x;  // exactly 2*16*2048*64
  int i = idx & 63;
  int s = (idx >> 6) & 2047;
  float ang = (float)s * exp2f(-(float)i * 0.2076205059304703f);
  float sv, cv;
  sincosf(ang, &sv, &cv);
  u32 qu = q[idx];
  float a0 = bf2f((unsigned short)(qu & 0xffff)), a1 = bf2f((unsigned short)(qu >> 16));
  q[idx] = (u32)f2bf(a0 * cv - a1 * sv) | ((u32)f2bf(a1 * cv + a0 * sv) << 16);
  u32 ku = k[idx];
  float b0 = bf2f((unsigned short)(ku & 0xffff)), b1 = bf2f((unsigned short)(ku >> 16));
  k[idx] = (u32)f2bf(b0 * cv - b1 * sv) | ((u32)f2bf(b1 * cv + b0 * sv) << 16);
}

// ---------------- causal flash attention ----------------
__global__ __launch_bounds__(512) void attn_k(
    const unsigned short* __restrict__ qg, const unsigned short* __restrict__ kg,
    const unsigned short* __restrict__ vtg, unsigned short* __restrict__ ab) {
  __shared__ alignas(16) unsigned short Kl[64 * 128];   // [key][hd], swizzled
  __shared__ alignas(16) unsigned short Vl[128 * 64];   // [hd][key], swizzled
  __shared__ alignas(16) unsigned short Pl[8][16 * 72]; // per wave [qrow][key+pad]
  int bh = (int)blockIdx.x & 31;
  int pr = (int)blockIdx.x >> 5;
  int t = (int)threadIdx.x, l = t & 63, w = t >> 6;
  int g = l >> 4, ln = l & 15;
  int b = bh >> 4, h = bh & 15;
  const size_t bq0 = (size_t)bh * 2048 * 128;

#pragma unroll 1
  for (int half = 0; half < 2; ++half) {
    int qt = half ? 15 - pr : pr;
    int qbase = qt * 128;
    int qrow = qbase + w * 16 + ln;
    us8 qf[4];
#pragma unroll
    for (int kf = 0; kf < 4; ++kf)
      qf[kf] = *(const us8*)&qg[bq0 + (size_t)qrow * 128 + kf * 32 + g * 8];
    f32x4 o[8] = {};
    float mrow = -1e30f, lrow = 0.f;
    int nkt = (qbase >> 6) + 2;
#pragma unroll 1
    for (int kt = 0; kt < nkt; ++kt) {
      __syncthreads();
#pragma unroll
      for (int i = 0; i < 2; ++i) {
        int fb = i * 8192 + w * 1024;
        int flat = fb + l * 16;
        int row = flat >> 8, colb = flat & 255;
        int sc = colb ^ ((row & 7) << 4);  // pre-swizzled global source (m173)
        gload16(kg + (bq0 + (size_t)(kt * 64 + row) * 128 + (sc >> 1)), (char*)Kl + fb);
        int rv = flat >> 7, cv2 = flat & 127;
        int scv = cv2 ^ ((rv & 7) << 4);
        gload16(vtg + (bq0 + (size_t)rv * 2048 + kt * 64 + (scv >> 1)), (char*)Vl + fb);
      }
      __syncthreads();
      // S^T = K * Q^T : D[key_local][qrow_local]
      f32x4 st[4];
#pragma unroll
      for (int kfr = 0; kfr < 4; ++kfr) {
        f32x4 acc = {};
        int row = kfr * 16 + ln;
        int swz = (row & 7) << 4;
#pragma unroll
        for (int kf = 0; kf < 4; ++kf) {
          us8 kfrag = *(const us8*)((const char*)Kl + row * 256 + ((kf * 64 + g * 16) ^ swz));
          acc = MFMA16(kfrag, qf[kf], acc);
        }
        st[kfr] = acc;
      }
      float pmax = -1e30f;
#pragma unroll
      for (int kfr = 0; kfr < 4; ++kfr)
#pragma unroll
        for (int r = 0; r < 4; ++r) {
          int key = kt * 64 + kfr * 16 + g * 4 + r;
          float sv = key <= qrow ? st[kfr][r] * 0.08838834764831845f : -1e30f;
          st[kfr][r] = sv;
          pmax = fmaxf(pmax, sv);
        }
      pmax = fmaxf(pmax, __shfl_xor(pmax, 16));
      pmax = fmaxf(pmax, __shfl_xor(pmax, 32));
      if (__ballot(pmax > mrow + 8.f)) {
        float mnew = pmax > mrow + 8.f ? pmax : mrow;
        float corr = exp2f((mrow - mnew) * 1.44269504f);
        mrow = mnew;
        lrow *= corr;
#pragma unroll
        for (int r = 0; r < 4; ++r) {
          float cr = __shfl(corr, g * 4 + r);
#pragma unroll
          for (int nf = 0; nf < 8; ++nf) o[nf][r] *= cr;
        }
      }
      float lsum = 0.f;
#pragma unroll
      for (int kfr = 0; kfr < 4; ++kfr) {
        us4 pk;
#pragma unroll
        for (int r = 0; r < 4; ++r) {
          float p = exp2f((st[kfr][r] - mrow) * 1.44269504f);
          lsum += p;
          pk[r] = f2bf(p);
        }
        *(us4*)&Pl[w][ln * 72 + kfr * 16 + g * 4] = pk;
      }
      lsum += __shfl_xor(lsum, 16);
      lsum += __shfl_xor(lsum, 32);
      lrow += lsum;
#pragma unroll
      for (int kf2 = 0; kf2 < 2; ++kf2) {
        us8 pa = *(const us8*)&Pl[w][ln * 72 + kf2 * 32 + g * 8];
#pragma unroll
        for (int nf = 0; nf < 8; ++nf) {
          int row = nf * 16 + ln;
          us8 vb = *(const us8*)((const char*)Vl + row * 128 +
                                 ((kf2 * 64 + g * 16) ^ ((row & 7) << 4)));
          o[nf] = MFMA16(pa, vb, o[nf]);
        }
      }
    }  // kt
    float invl = 1.f / lrow;
#pragma unroll
    for (int r = 0; r < 4; ++r) {
      float ir = __shfl(invl, g * 4 + r);
      int srow = qbase + w * 16 + g * 4 + r;
      size_t base = ((size_t)b * 2048 + srow) * 2048 + h * 128 + ln;
#pragma unroll
      for (int nf = 0; nf < 8; ++nf) ab[base + (size_t)nf * 16] = f2bf(o[nf][r] * ir);
    }
  }  // half
}

extern "C" void kernel_launch(void* const* d_in, const int* in_sizes, int n_in,
                              void* d_out, int out_size, void* d_ws, size_t ws_size,
                              hipStream_t stream) {
  const float* x  = (const float*)d_in[0];
  const float* Wq = (const float*)d_in[1];
  const float* bq = (const float*)d_in[2];
  const float* Wk = (const float*)d_in[3];
  const float* Wv = (const float*)d_in[4];
  const float* bv = (const float*)d_in[5];
  const float* Wo = (const float*)d_in[6];
  const float* bo = (const float*)d_in[7];
  float* out = (float*)d_out;

  unsigned short* ws = (unsigned short*)d_ws;
  unsigned short* xb   = ws;                // 8388608 elems (x bf16; later reused as attn out)
  unsigned short* wcat = xb + 8388608;      // 12582912 (Wq|Wk|Wv rows, [6144][2048])
  unsigned short* wob  = wcat + 12582912;   // 4194304
  unsigned short* qb   = wob + 4194304;     // 8388608  [32][2048][128]
  unsigned short* kb   = qb + 8388608;      // 8388608
  unsigned short* vtb  = kb + 8388608;      // 8388608  [32][128][2048] (transposed)

  convert_all<<<2048, 256, 0, stream>>>(x, Wq, Wk, Wv, Wo, xb, wcat, wob);
  gemm2<0><<<768, 512, 0, stream>>>(xb, wcat, 24, 6144,
                                    nullptr, nullptr, qb, kb, vtb, bq, bv);
  rope_k<<<16384, 256, 0, stream>>>((u32*)qb, (u32*)kb);
  attn_k<<<256, 512, 0, stream>>>(qb, kb, vtb, xb /* a_buf alias */);
  gemm2<1><<<256, 512, 0, stream>>>(xb, wob, 8, 2048,
                                    out, bo, nullptr, nullptr, nullptr, nullptr, nullptr);
}